// Round 11
// baseline (335.017 us; speedup 1.0000x reference)
//
#include <hip/hip_runtime.h>
#include <hip/hip_bf16.h>
#include <stdint.h>

#define NN 50000     // nodes
#define NE 640000    // edges
#define NR 8         // relations
#define NK (NR * NN) // 400000 (rel,dst) keys
#define NB2 ((NK + 1023) / 1024)   // 391 scan blocks

typedef short bf16x8 __attribute__((ext_vector_type(8)));
typedef float f32x4  __attribute__((ext_vector_type(4)));

__device__ __forceinline__ unsigned short f2bf(float f) {
    union { float f; unsigned u; } v; v.f = f;
    unsigned r = v.u + 0x7FFF + ((v.u >> 16) & 1);
    return (unsigned short)(r >> 16);
}

// ---------------- fused prep: hist2 + cvt_bf16 + prepW1 + prepW2 ----------------
// blockIdx ranges: [0,2500) hist; [2500,5625) cvt; [5625,6201) prepW<128>; [6201,6489) prepW<64>.
__global__ __launch_bounds__(256) void prep_all(
        const int* __restrict__ dst, const int* __restrict__ et, int* __restrict__ counts,
        const float* __restrict__ X, unsigned short* __restrict__ Xbf,
        const float* __restrict__ W1, const float* __restrict__ W1s, unsigned short* __restrict__ W1T,
        const float* __restrict__ W2, const float* __restrict__ W2s, unsigned short* __restrict__ W2T) {
    int b = blockIdx.x, t = threadIdx.x;
    if (b < 2500) {                               // histogram over (rel,dst) keys
        int e = b * 256 + t;
        atomicAdd(&counts[et[e] * NN + dst[e]], 1);
    } else if (b < 5625) {                        // X fp32 -> bf16, 8 elems/thread
        int i = (b - 2500) * 256 + t;             // 800000 = NN*128/8
        const float4* pp = (const float4*)X + (size_t)i * 2;
        float4 a = pp[0], c = pp[1];
        uint4 o;
        o.x = (unsigned)f2bf(a.x) | ((unsigned)f2bf(a.y) << 16);
        o.y = (unsigned)f2bf(a.z) | ((unsigned)f2bf(a.w) << 16);
        o.z = (unsigned)f2bf(c.x) | ((unsigned)f2bf(c.y) << 16);
        o.w = (unsigned)f2bf(c.z) | ((unsigned)f2bf(c.w) << 16);
        ((uint4*)Xbf)[i] = o;
    } else if (b < 6201) {                        // W1T[(r*128+o)][k]; r==8 -> W1s
        int idx = (b - 5625) * 256 + t;           // 147456 = 9*128*128
        int k = idx & 127, c = idx >> 7;
        int r = c >> 7, o = c & 127;
        float v = (r < 8) ? W1[((size_t)r * 128 + k) * 128 + o]
                          : W1s[(size_t)k * 128 + o];
        W1T[idx] = f2bf(v);
    } else {                                      // W2T[(r*64+o)][k]; r==8 -> W2s
        int idx = (b - 6201) * 256 + t;           // 73728 = 9*64*128
        int k = idx & 127, c = idx >> 7;
        int r = c / 64, o = c - r * 64;
        float v = (r < 8) ? W2[((size_t)r * 128 + k) * 64 + o]
                          : W2s[(size_t)k * 64 + o];
        W2T[idx] = f2bf(v);
    }
}

// ---------------- scan chain over counts (NK keys) ----------------
__global__ __launch_bounds__(1024) void blocksum_kernel(const int* __restrict__ counts,
                                                        int* __restrict__ bsum, int n) {
    __shared__ int ws[16];
    int i = blockIdx.x * 1024 + threadIdx.x;
    int v = (i < n) ? counts[i] : 0;
    #pragma unroll
    for (int d = 32; d > 0; d >>= 1) v += __shfl_down(v, d, 64);
    int wid = threadIdx.x >> 6, lane = threadIdx.x & 63;
    if (lane == 0) ws[wid] = v;
    __syncthreads();
    if (threadIdx.x < 16) {
        int s = ws[threadIdx.x];
        #pragma unroll
        for (int d = 8; d > 0; d >>= 1) s += __shfl_down(s, d, 16);
        if (threadIdx.x == 0) bsum[blockIdx.x] = s;
    }
}

__global__ __launch_bounds__(512) void scanbase_kernel(const int* __restrict__ bsum,
                                                       int* __restrict__ base,
                                                       int* __restrict__ total, int nb) {
    __shared__ int ws[8];
    int t = threadIdx.x, lane = t & 63, wid = t >> 6;
    int v = (t < nb) ? bsum[t] : 0;
    int incl = v;
    #pragma unroll
    for (int d = 1; d < 64; d <<= 1) {
        int nv = __shfl_up(incl, d, 64);
        if (lane >= d) incl += nv;
    }
    if (lane == 63) ws[wid] = incl;
    __syncthreads();
    if (t < 8) {
        int s = ws[t], si = s;
        #pragma unroll
        for (int d = 1; d < 8; d <<= 1) {
            int nv = __shfl_up(si, d, 64);
            if (t >= d) si += nv;
        }
        ws[t] = si - s;   // exclusive wave base
    }
    __syncthreads();
    int excl = ws[wid] + incl - v;
    if (t < nb) base[t] = excl;
    if (t == 511) total[0] = ws[7] + incl;
}

__global__ __launch_bounds__(1024) void scanlocal_kernel(const int* __restrict__ counts,
                                                         const int* __restrict__ base,
                                                         int* __restrict__ offsets,
                                                         int* __restrict__ cursor, int n) {
    __shared__ int ws[16];
    __shared__ int wbase[16];
    int t = threadIdx.x;
    int i = blockIdx.x * 1024 + t;
    int v = (i < n) ? counts[i] : 0;
    int lane = t & 63, wid = t >> 6;
    int incl = v;
    #pragma unroll
    for (int d = 1; d < 64; d <<= 1) {
        int nv = __shfl_up(incl, d, 64);
        if (lane >= d) incl += nv;
    }
    if (lane == 63) ws[wid] = incl;
    __syncthreads();
    if (t < 16) {
        int s = ws[t], si = s;
        #pragma unroll
        for (int d = 1; d < 16; d <<= 1) {
            int nv = __shfl_up(si, d, 16);
            if (t >= d) si += nv;
        }
        wbase[t] = si - s;
    }
    __syncthreads();
    if (i < n) {
        int excl = base[blockIdx.x] + wbase[wid] + incl - v;
        offsets[i] = excl;
        cursor[i]  = excl;
    }
}

__global__ void fill2_kernel(const int* __restrict__ src, const int* __restrict__ dst,
                             const int* __restrict__ et, int* __restrict__ cursor,
                             int* __restrict__ esrc) {
    int e = blockIdx.x * 256 + threadIdx.x;
    if (e < NE) {
        int pos = atomicAdd(&cursor[et[e] * NN + dst[e]], 1);
        esrc[pos] = src[e];
    }
}

// ---------------- Fused aggregate + transform layer (2 relations per pass) ----------------
// Per block: 64 dst nodes, 256 threads. Thread owns (key=t>>2, 32 cols=t&3).
// Each pass gathers TWO relations' segments as two interleaved 2-deep chains
// (4 real row-loads in flight; imbalance drained per-chain, no dummy loads),
// packs both tiles, one barrier pair, MFMAs both. Convoy stalls: 4 (was 8).
template<int NOUT, bool RELU, bool OUTBF16>
__global__ __launch_bounds__(256) void fused_layer(
        const unsigned short* __restrict__ A,    // [M][128] bf16 node features
        const unsigned short* __restrict__ WT,   // [9*NOUT][128] bf16
        const float* __restrict__ bias,          // [NOUT]
        const int* __restrict__ off2,            // [NK+1]
        const int* __restrict__ esrc,            // [NE] src sorted by (rel,dst)
        void* __restrict__ outp, int M) {
    constexpr int CW = NOUT / 4;      // cols per wave (MFMA)
    constexpr int NJ = CW / 16;       // n-tiles per wave
    __shared__ unsigned short Asw[2][64 * 128];   // 2 x 16 KB swizzled tiles

    const int t = threadIdx.x;
    const int n0 = blockIdx.x * 64;
    const int bm = (M - n0 < 64) ? (M - n0) : 64;
    const int lane = t & 63;
    const int w = t >> 6;
    const int r15 = lane & 15;
    const int q = lane >> 4;

    const int key = t >> 2;          // local dst row 0..63
    const int sub = t & 3;           // col group: uints [sub*16, sub*16+16)
    const int kk = n0 + key;
    const bool kv = (kk < M);

    f32x4 acc[4][NJ] = {};

    auto do_mfma = [&](int b, int rr) {
        #pragma unroll
        for (int ks = 0; ks < 4; ks++) {
            int c = (ks * 4 + q) ^ r15;
            bf16x8 af[4];
            #pragma unroll
            for (int i = 0; i < 4; i++)
                af[i] = *(const bf16x8*)((const char*)Asw[b] + (i * 16 + r15) * 256 + (c << 4));
            #pragma unroll
            for (int j = 0; j < NJ; j++) {
                bf16x8 bf = *(const bf16x8*)(WT +
                    ((size_t)(rr * NOUT + w * CW + j * 16 + r15) << 7) + ks * 32 + q * 8);
                #pragma unroll
                for (int i = 0; i < 4; i++)
                    acc[i][j] = __builtin_amdgcn_mfma_f32_16x16x32_bf16(af[i], bf, acc[i][j], 0, 0, 0);
            }
        }
    };

    auto accum32 = [&](float* a, const uint4* v, float wt) {
        #pragma unroll
        for (int u = 0; u < 4; u++) {
            unsigned uu[4] = {v[u].x, v[u].y, v[u].z, v[u].w};
            #pragma unroll
            for (int j = 0; j < 4; j++) {
                a[u * 8 + j * 2 + 0] = fmaf(wt, __uint_as_float(uu[j] << 16), a[u * 8 + j * 2 + 0]);
                a[u * 8 + j * 2 + 1] = fmaf(wt, __uint_as_float(uu[j] & 0xffff0000u), a[u * 8 + j * 2 + 1]);
            }
        }
    };

    const unsigned* base = (const unsigned*)A;

    // prefetch rel 0/1 segment bounds
    int eA0 = kv ? off2[kk] : 0;
    int eA1 = kv ? off2[kk + 1] : 0;
    int eB0 = kv ? off2[NN + kk] : 0;
    int eB1 = kv ? off2[NN + kk + 1] : 0;

    // ---- self pass (K-chunk index 8) into buf 0 ----
    #pragma unroll
    for (int kc = 0; kc < 4; kc++) {
        int g = t + kc * 256;           // 1024 chunks = 64 rows x 16
        int row = g >> 4, c = g & 15;
        uint4 v = make_uint4(0, 0, 0, 0);
        if (row < bm) v = *(const uint4*)(A + ((size_t)(n0 + row) << 7) + c * 8);
        *(uint4*)((char*)Asw[0] + row * 256 + ((c ^ (row & 15)) << 4)) = v;
    }
    __syncthreads();
    do_mfma(0, 8);

    // ---- 4 dual-relation passes ----
    #pragma unroll 1
    for (int p = 0; p < 4; p++) {
        const int rA = 2 * p, rB = 2 * p + 1;
        // prefetch next pass bounds
        int nA0 = 0, nA1 = 0, nB0 = 0, nB1 = 0;
        if (p < 3 && kv) {
            nA0 = off2[(rA + 2) * NN + kk];
            nA1 = off2[(rA + 2) * NN + kk + 1];
            nB0 = off2[(rB + 2) * NN + kk];
            nB1 = off2[(rB + 2) * NN + kk + 1];
        }

        float a0[32], a1[32];
        #pragma unroll
        for (int i = 0; i < 32; i++) { a0[i] = 0.f; a1[i] = 0.f; }

        int eA = eA0, eB = eB0;
        // joint loop: both chains active -> 4 independent row loads in flight
        while (eA < eA1 && eB < eB1) {
            int av = (eA + 1 < eA1) ? 1 : 0;
            int bv = (eB + 1 < eB1) ? 1 : 0;
            int sA0 = esrc[eA], sA1 = esrc[eA + av];
            int sB0 = esrc[eB], sB1 = esrc[eB + bv];
            const uint4* pA0 = (const uint4*)(base + ((size_t)sA0 << 6) + sub * 16);
            const uint4* pA1 = (const uint4*)(base + ((size_t)sA1 << 6) + sub * 16);
            const uint4* pB0 = (const uint4*)(base + ((size_t)sB0 << 6) + sub * 16);
            const uint4* pB1 = (const uint4*)(base + ((size_t)sB1 << 6) + sub * 16);
            uint4 vA0[4], vA1[4], vB0[4], vB1[4];
            #pragma unroll
            for (int u = 0; u < 4; u++) vA0[u] = pA0[u];
            #pragma unroll
            for (int u = 0; u < 4; u++) vA1[u] = pA1[u];
            #pragma unroll
            for (int u = 0; u < 4; u++) vB0[u] = pB0[u];
            #pragma unroll
            for (int u = 0; u < 4; u++) vB1[u] = pB1[u];
            accum32(a0, vA0, 1.f); accum32(a0, vA1, av ? 1.f : 0.f);
            accum32(a1, vB0, 1.f); accum32(a1, vB1, bv ? 1.f : 0.f);
            eA += 2; eB += 2;
        }
        // drain leftover chain (at most one of these runs)
        while (eA < eA1) {
            int av = (eA + 1 < eA1) ? 1 : 0;
            int sA0 = esrc[eA], sA1 = esrc[eA + av];
            const uint4* pA0 = (const uint4*)(base + ((size_t)sA0 << 6) + sub * 16);
            const uint4* pA1 = (const uint4*)(base + ((size_t)sA1 << 6) + sub * 16);
            uint4 vA0[4], vA1[4];
            #pragma unroll
            for (int u = 0; u < 4; u++) vA0[u] = pA0[u];
            #pragma unroll
            for (int u = 0; u < 4; u++) vA1[u] = pA1[u];
            accum32(a0, vA0, 1.f); accum32(a0, vA1, av ? 1.f : 0.f);
            eA += 2;
        }
        while (eB < eB1) {
            int bv = (eB + 1 < eB1) ? 1 : 0;
            int sB0 = esrc[eB], sB1 = esrc[eB + bv];
            const uint4* pB0 = (const uint4*)(base + ((size_t)sB0 << 6) + sub * 16);
            const uint4* pB1 = (const uint4*)(base + ((size_t)sB1 << 6) + sub * 16);
            uint4 vB0[4], vB1[4];
            #pragma unroll
            for (int u = 0; u < 4; u++) vB0[u] = pB0[u];
            #pragma unroll
            for (int u = 0; u < 4; u++) vB1[u] = pB1[u];
            accum32(a1, vB0, 1.f); accum32(a1, vB1, bv ? 1.f : 0.f);
            eB += 2;
        }
        __syncthreads();   // all waves done reading Asw from previous MFMA

        // pack both tiles (c = sub*4 + c4, XOR-swizzled rows)
        #pragma unroll
        for (int c4 = 0; c4 < 4; ++c4) {
            int c = sub * 4 + c4;
            int off = key * 256 + ((c ^ (key & 15)) << 4);
            uint4 p0, p1;
            p0.x = (unsigned)f2bf(a0[c4 * 8 + 0]) | ((unsigned)f2bf(a0[c4 * 8 + 1]) << 16);
            p0.y = (unsigned)f2bf(a0[c4 * 8 + 2]) | ((unsigned)f2bf(a0[c4 * 8 + 3]) << 16);
            p0.z = (unsigned)f2bf(a0[c4 * 8 + 4]) | ((unsigned)f2bf(a0[c4 * 8 + 5]) << 16);
            p0.w = (unsigned)f2bf(a0[c4 * 8 + 6]) | ((unsigned)f2bf(a0[c4 * 8 + 7]) << 16);
            p1.x = (unsigned)f2bf(a1[c4 * 8 + 0]) | ((unsigned)f2bf(a1[c4 * 8 + 1]) << 16);
            p1.y = (unsigned)f2bf(a1[c4 * 8 + 2]) | ((unsigned)f2bf(a1[c4 * 8 + 3]) << 16);
            p1.z = (unsigned)f2bf(a1[c4 * 8 + 4]) | ((unsigned)f2bf(a1[c4 * 8 + 5]) << 16);
            p1.w = (unsigned)f2bf(a1[c4 * 8 + 6]) | ((unsigned)f2bf(a1[c4 * 8 + 7]) << 16);
            *(uint4*)((char*)Asw[0] + off) = p0;
            *(uint4*)((char*)Asw[1] + off) = p1;
        }
        __syncthreads();

        do_mfma(0, rA);
        do_mfma(1, rB);
        eA0 = nA0; eA1 = nA1; eB0 = nB0; eB1 = nB1;
    }

    // ---- epilogue: + bias, optional ReLU, store ----
    #pragma unroll
    for (int j = 0; j < NJ; j++) {
        int col = w * CW + j * 16 + r15;
        float bv = bias[col];
        #pragma unroll
        for (int i = 0; i < 4; i++) {
            #pragma unroll
            for (int reg = 0; reg < 4; reg++) {
                int m = n0 + i * 16 + q * 4 + reg;
                if (m < M) {
                    float v = acc[i][j][reg] + bv;
                    if (RELU) v = fmaxf(v, 0.f);
                    if (OUTBF16)
                        ((unsigned short*)outp)[(size_t)m * NOUT + col] = f2bf(v);
                    else
                        ((float*)outp)[(size_t)m * NOUT + col] = v;
                }
            }
        }
    }
}

extern "C" void kernel_launch(void* const* d_in, const int* in_sizes, int n_in,
                              void* d_out, int out_size, void* d_ws, size_t ws_size,
                              hipStream_t stream) {
    const float* X   = (const float*)d_in[0];
    const int*   src = (const int*)d_in[1];
    const int*   dst = (const int*)d_in[2];
    const int*   et  = (const int*)d_in[3];
    const float* W1  = (const float*)d_in[4];
    const float* W1s = (const float*)d_in[5];
    const float* b1  = (const float*)d_in[6];
    const float* W2  = (const float*)d_in[7];
    const float* W2s = (const float*)d_in[8];
    const float* b2  = (const float*)d_in[9];
    float* out = (float*)d_out;

    // workspace carve (~34 MB)
    char* p = (char*)d_ws;
    unsigned short* Xbf = (unsigned short*)p; p += (size_t)NN * 128 * 2;       // 12.8 MB
    unsigned short* hbf = (unsigned short*)p; p += (size_t)NN * 128 * 2;       // 12.8 MB
    unsigned short* W1T = (unsigned short*)p; p += (size_t)9 * 128 * 128 * 2;  // 288 KB
    unsigned short* W2T = (unsigned short*)p; p += (size_t)9 * 64 * 128 * 2;   // 144 KB
    int* counts2 = (int*)p; p += (size_t)NK * 4;                               // 1.6 MB
    int* off2    = (int*)p; p += (size_t)(NK + 4) * 4;                         // 1.6 MB
    int* cursor2 = (int*)p; p += (size_t)NK * 4;                               // 1.6 MB
    int* esrc    = (int*)p; p += (size_t)(NE + 16) * 4;                        // 2.56 MB
    int* bsum    = (int*)p; p += 512 * 4;
    int* bbase   = (int*)p; p += 512 * 4;

    // zero counts, then fused prep (hist + cvt + both weight transposes)
    hipMemsetAsync(counts2, 0, (size_t)NK * sizeof(int), stream);
    prep_all<<<6489, 256, 0, stream>>>(dst, et, counts2, X, Xbf,
                                       W1, W1s, W1T, W2, W2s, W2T);

    // (rel,dst)-sorted CSR
    blocksum_kernel<<<NB2, 1024, 0, stream>>>(counts2, bsum, NK);
    scanbase_kernel<<<1, 512, 0, stream>>>(bsum, bbase, &off2[NK], NB2);
    scanlocal_kernel<<<NB2, 1024, 0, stream>>>(counts2, bbase, off2, cursor2, NK);
    fill2_kernel<<<(NE + 255) / 256, 256, 0, stream>>>(src, dst, et, cursor2, esrc);

    const int nblk = (NN + 63) / 64;  // 782

    // Layer 1: h = relu(agg1 + X@W1s + b1), stored bf16
    fused_layer<128, true, true><<<nblk, 256, 0, stream>>>(
        Xbf, W1T, b1, off2, esrc, hbf, NN);
    // Layer 2: out = agg2 + h@W2s + b2, fp32
    fused_layer<64, false, false><<<nblk, 256, 0, stream>>>(
        hbf, W2T, b2, off2, esrc, out, NN);
}